// Round 16
// baseline (430.906 us; speedup 1.0000x reference)
//
#include <hip/hip_runtime.h>

// RelativeAttention B=8, N=2048, D=512, fp32 in, (out[B,N,D], p[B,N,N]) fp32 out.
//
// Round-16: r15 verbatim except the SCORE kernels get the r15 geometry lever:
// BM=256 x BN=128, 8 waves (4M x 2N), counted-vmcnt gl_lds core with
// 3 loads/wave/step (2 A + 1 B; was 4), vmcnt(6), 3 x 24KB LDS buffers.
// Rel band widens to 2303 (18 z-tiles), scatter j = bcg + ii - 255.
// Per-output-element accumulation order and cvt points unchanged ->
// absmax must be exactly 0.0859375. out_gemm9 (155.5us, r15-best) unchanged.

#define SEQN 2048
#define DD   512
#define NB   8
#define WROWS 4095   // 2N-1
#define WPAD  4096   // padded row stride for wvT

typedef float     f32x4 __attribute__((ext_vector_type(4)));
typedef _Float16  h16x4 __attribute__((ext_vector_type(4)));
typedef _Float16  h16x8 __attribute__((ext_vector_type(8)));

__device__ __forceinline__ unsigned swzw(int row, int c4) {
  unsigned b = (unsigned)(row * 64 + c4 * 8);
  return b ^ (((unsigned)row & 6u) << 3);
}
__device__ __forceinline__ unsigned swzr(int row, int kg) {
  unsigned b = (unsigned)(row * 64 + kg * 16);
  return b ^ (((unsigned)row & 6u) << 3);
}

typedef const __attribute__((address_space(1))) unsigned int gu32_t;
typedef __attribute__((address_space(3))) unsigned int lu32_t;
__device__ __forceinline__ void gload_lds16(const void* g, void* l) {
  __builtin_amdgcn_global_load_lds((gu32_t*)g, (lu32_t*)l, 16, 0, 0);
}

// ---------------------------------------------------------------------------
// 8-wave counted-vmcnt gl_lds core: 256x128 tile, K-step 32 (64 B/row f16),
// 3 LDS buffers of 24 KB (A 16KB at +0, B 8KB at +16384). Per wave per step:
// 2 A gl_lds + 1 B gl_lds -> vmcnt(6) = 2 tiles x 3 loads in flight.
// Read-side XOR swizzle applied by pre-swizzling the per-lane GLOBAL chunk.
// ---------------------------------------------------------------------------
template <class P>
__device__ __forceinline__ void stage_tile8(const P& prov, char* smem, int buf,
                                            int t, int wave, int l4, int cp) {
  char* lb = smem + buf * 24576;
#pragma unroll
  for (int h = 0; h < 2; h++) {
    int R = wave * 32 + h * 16;           // A rows [0,256)
    int row = R + l4;
    int c = cp ^ ((row >> 1) & 3);
    gload_lds16((const char*)prov.a_src(t, row) + c * 16, lb + R * 64);
  }
  {
    int RB = wave * 16;                   // B rows [0,128)
    int rowb = RB + l4;
    int cb = cp ^ ((rowb >> 1) & 3);
    gload_lds16((const char*)prov.b_src(t, rowb) + cb * 16, lb + 16384 + RB * 64);
  }
}

template <int NT, class P>
__device__ __forceinline__ void gemm_core8(const P& prov, char* smem, f32x4 (&acc)[4][4]) {
  const int tid = threadIdx.x;
  const int lane = tid & 63, wave = tid >> 6;
  const int l4 = lane >> 2, cp = lane & 3;
  const int wm = wave >> 1, wn = wave & 1;      // 4M x 2N
  const int r16 = lane & 15, kg = lane >> 4;

  stage_tile8(prov, smem, 0, 0, wave, l4, cp);
  stage_tile8(prov, smem, 1, 1, wave, l4, cp);
  stage_tile8(prov, smem, 2, 2, wave, l4, cp);

  int buf = 0;
  for (int t = 0; t < NT; t++) {
    asm volatile("s_waitcnt vmcnt(6)" ::: "memory");
    __builtin_amdgcn_s_barrier();
    char* lb = smem + buf * 24576;
    h16x8 af[4], bf[4];
#pragma unroll
    for (int mf = 0; mf < 4; mf++)
      af[mf] = *(const h16x8*)(lb + swzr(wm * 64 + mf * 16 + r16, kg));
#pragma unroll
    for (int nf = 0; nf < 4; nf++)
      bf[nf] = *(const h16x8*)(lb + 16384 + swzr(wn * 64 + nf * 16 + r16, kg));
#pragma unroll
    for (int mf = 0; mf < 4; mf++)
#pragma unroll
      for (int nf = 0; nf < 4; nf++)
        acc[mf][nf] = __builtin_amdgcn_mfma_f32_16x16x32_f16(af[mf], bf[nf], acc[mf][nf], 0, 0, 0);
    asm volatile("s_waitcnt lgkmcnt(0)" ::: "memory");
    __builtin_amdgcn_s_barrier();
    int nt2 = t + 3; if (nt2 >= NT) nt2 = NT - 1;   // clamped restage keeps vmcnt uniform
    stage_tile8(prov, smem, buf, nt2, wave, l4, cp);
    buf = (buf == 2) ? 0 : buf + 1;
  }
}

// ---------------- providers -------------------------------------------------
struct ProvQK {   // base: A=qh rows [i0,i0+256), B=kh rows [j0,j0+128)
  const char *ar, *br;
  __device__ __forceinline__ const void* a_src(int t, int row) const {
    return ar + (size_t)row * 1024 + (size_t)t * 64;
  }
  __device__ __forceinline__ const void* b_src(int t, int row) const {
    return br + (size_t)row * 1024 + (size_t)t * 64;
  }
};
struct ProvRel {  // rel: A=qh rows [i0,i0+256), B=wkh band rows (clamped)
  const char *ar, *wk; int tb;
  __device__ __forceinline__ const void* a_src(int t, int row) const {
    return ar + (size_t)row * 1024 + (size_t)t * 64;
  }
  __device__ __forceinline__ const void* b_src(int t, int row) const {
    int tr = tb + row; if (tr > WROWS - 1) tr = WROWS - 1;
    return wk + (size_t)tr * 1024 + (size_t)t * 64;
  }
};

// ---------------- f32 -> f16 bulk convert -----------------------------------
__global__ __launch_bounds__(256) void cvt_f16_k(const float* __restrict__ in,
                                                 _Float16* __restrict__ out, long n8) {
  for (long i = (long)blockIdx.x * 256 + threadIdx.x; i < n8; i += (long)gridDim.x * 256) {
    f32x4 a = ((const f32x4*)in)[i * 2];
    f32x4 b = ((const f32x4*)in)[i * 2 + 1];
    h16x8 h = {(_Float16)a[0], (_Float16)a[1], (_Float16)a[2], (_Float16)a[3],
               (_Float16)b[0], (_Float16)b[1], (_Float16)b[2], (_Float16)b[3]};
    ((h16x8*)out)[i] = h;
  }
}

// ---------------- transpose v [B,N,D] f32 -> vT [B,D,N] f16 ----------------
__global__ __launch_bounds__(256) void transpose_v_k(const float* __restrict__ v,
                                                     _Float16* __restrict__ vT) {
  __shared__ float tile[32][33];
  const int d0 = blockIdx.x * 32, j0 = blockIdx.y * 32, b = blockIdx.z;
  const int tid = threadIdx.x;
#pragma unroll
  for (int rep = 0; rep < 4; rep++) {
    int idx = rep * 256 + tid;
    int rr = idx >> 5, cc = idx & 31;
    tile[rr][cc] = v[((size_t)(b * SEQN + j0 + rr)) * DD + d0 + cc];
  }
  __syncthreads();
#pragma unroll
  for (int rep = 0; rep < 4; rep++) {
    int idx = rep * 256 + tid;
    int rr = idx >> 5, cc = idx & 31;
    vT[((size_t)(b * DD + d0 + rr)) * SEQN + j0 + cc] = (_Float16)tile[cc][rr];
  }
}

// ------------- transpose w_v [4095,512] f32 -> wvT [512,4096] f16 -----------
__global__ __launch_bounds__(256) void transpose_wv_k(const float* __restrict__ wv,
                                                      _Float16* __restrict__ wvT) {
  __shared__ float tile[32][33];
  const int d0 = blockIdx.x * 32, r0 = blockIdx.y * 32;
  const int tid = threadIdx.x;
#pragma unroll
  for (int rep = 0; rep < 4; rep++) {
    int idx = rep * 256 + tid;
    int rr = idx >> 5, cc = idx & 31;
    float val = 0.f;
    if (r0 + rr < WROWS) val = wv[(size_t)(r0 + rr) * DD + d0 + cc];
    tile[rr][cc] = val;
  }
  __syncthreads();
#pragma unroll
  for (int rep = 0; rep < 4; rep++) {
    int idx = rep * 256 + tid;
    int rr = idx >> 5, cc = idx & 31;
    wvT[(size_t)(d0 + rr) * WPAD + r0 + cc] = (_Float16)tile[cc][rr];
  }
}

// ---------------- score kernels: 8-wave 256x128 gl_lds core -----------------
__global__ __launch_bounds__(512) void score_base3_k(const _Float16* __restrict__ qh,
                                                     const _Float16* __restrict__ kh,
                                                     float* __restrict__ S) {
  __shared__ __align__(16) char smem[73728];
  const int j0 = blockIdx.x * 128, i0 = blockIdx.y * 256, b = blockIdx.z;
  const int tid = threadIdx.x, lane = tid & 63, wave = tid >> 6;
  const int wm = wave >> 1, wn = wave & 1, r16 = lane & 15, kg = lane >> 4;

  f32x4 acc[4][4];
#pragma unroll
  for (int mf = 0; mf < 4; mf++)
#pragma unroll
    for (int nf = 0; nf < 4; nf++) acc[mf][nf] = (f32x4){0.f, 0.f, 0.f, 0.f};

  ProvQK prov{(const char*)(qh + (size_t)(b * SEQN + i0) * DD),
              (const char*)(kh + (size_t)(b * SEQN + j0) * DD)};
  gemm_core8<16>(prov, smem, acc);

#pragma unroll
  for (int mf = 0; mf < 4; mf++)
#pragma unroll
    for (int nf = 0; nf < 4; nf++)
#pragma unroll
      for (int r = 0; r < 4; r++) {
        int ii = wm * 64 + mf * 16 + kg * 4 + r;   // [0,256)
        int jj = wn * 64 + nf * 16 + r16;          // [0,128)
        S[(size_t)(b * SEQN + i0 + ii) * SEQN + j0 + jj] = acc[mf][nf][r];
      }
}

__global__ __launch_bounds__(512) void score_rel3_k(const _Float16* __restrict__ qh,
                                                    const _Float16* __restrict__ wkh,
                                                    float* __restrict__ S) {
  __shared__ __align__(16) char smem[73728];
  const int z = blockIdx.x, i0 = blockIdx.y * 256, b = blockIdx.z;
  const int tid = threadIdx.x, lane = tid & 63, wave = tid >> 6;
  const int wm = wave >> 1, wn = wave & 1, r16 = lane & 15, kg = lane >> 4;
  const int tmin = SEQN - 256 - i0;   // first band row (>= 0)

  f32x4 acc[4][4];
#pragma unroll
  for (int mf = 0; mf < 4; mf++)
#pragma unroll
    for (int nf = 0; nf < 4; nf++) acc[mf][nf] = (f32x4){0.f, 0.f, 0.f, 0.f};

  ProvRel prov{(const char*)(qh + (size_t)(b * SEQN + i0) * DD),
               (const char*)wkh, tmin + z * 128};
  gemm_core8<16>(prov, smem, acc);

  // scatter-add: band col bc -> j = bc + ii - 255 ; band width 2303
#pragma unroll
  for (int mf = 0; mf < 4; mf++)
#pragma unroll
    for (int nf = 0; nf < 4; nf++) {
      int bcg = z * 128 + wn * 64 + nf * 16 + r16;
#pragma unroll
      for (int r = 0; r < 4; r++) {
        int ii = wm * 64 + mf * 16 + kg * 4 + r;
        int j = bcg + ii - 255;
        if (bcg <= 2302 && j >= 0 && j < SEQN)
          S[(size_t)(b * SEQN + i0 + ii) * SEQN + j] += acc[mf][nf][r];
      }
    }
}

// ---------------- softmax over rows of S (in place -> p) --------------------
__global__ __launch_bounds__(256) void softmax_rows_k(float* __restrict__ S) {
  const int wid = threadIdx.x >> 6, lane = threadIdx.x & 63;
  const size_t row = (size_t)blockIdx.x * 4 + wid;
  float* p = S + row * SEQN;
  f32x4 x[8];
  float m = -3.4e38f;
#pragma unroll
  for (int c = 0; c < 8; c++) {
    x[c] = *(const f32x4*)(p + c * 256 + lane * 4);
    m = fmaxf(m, fmaxf(fmaxf(x[c][0], x[c][1]), fmaxf(x[c][2], x[c][3])));
  }
#pragma unroll
  for (int off = 32; off > 0; off >>= 1) m = fmaxf(m, __shfl_xor(m, off));
  float s = 0.f;
#pragma unroll
  for (int c = 0; c < 8; c++)
#pragma unroll
    for (int e = 0; e < 4; e++) {
      x[c][e] = __expf(x[c][e] - m);
      s += x[c][e];
    }
#pragma unroll
  for (int off = 32; off > 0; off >>= 1) s += __shfl_xor(s, off);
  float inv = 1.f / s;
#pragma unroll
  for (int c = 0; c < 8; c++) {
    x[c][0] *= inv; x[c][1] *= inv; x[c][2] *= inv; x[c][3] *= inv;
    *(f32x4*)(p + c * 256 + lane * 4) = x[c];
  }
}

// ------- out = p.v + skew(p).w_v — BM=256 x BN=128, 8 waves (r15 best) ------
__global__ __launch_bounds__(512) void out_gemm9_k(const float* __restrict__ S,
                                                   const _Float16* __restrict__ vT,
                                                   const _Float16* __restrict__ wvT,
                                                   float* __restrict__ outp) {
  __shared__ __align__(16) char smem[49152];
  const int bid = blockIdx.x;
  const int xcd = bid & 7, rr = bid >> 3;
  const int x = rr & 3, s8 = rr >> 2;
  const int rt = xcd + 8 * s8;               // [0,64): row-tile, bijective
  const int d0 = x * 128, b = rt >> 3, i0 = (rt & 7) * 256;
  const int tid = threadIdx.x, lane = tid & 63, wave = tid >> 6;
  const int wm = wave >> 1, wn = wave & 1, r16 = lane & 15, kg = lane >> 4;
  const int tmin = SEQN - 256 - i0;

  const float*    pb = S  + (size_t)(b * SEQN + i0) * SEQN;
  const _Float16* vb = vT + (size_t)(b * DD + d0) * SEQN;
  const _Float16* wb = wvT + (size_t)d0 * WPAD + tmin;

  f32x4 acc[4][4];
#pragma unroll
  for (int mf = 0; mf < 4; mf++)
#pragma unroll
    for (int nf = 0; nf < 4; nf++) acc[mf][nf] = (f32x4){0.f, 0.f, 0.f, 0.f};

  f32x4 ra[4];
  h16x4 rbv[2];

  auto LOADREGS = [&](int t) {
    if (t < 64) {
      const int k0 = t * 32;
#pragma unroll
      for (int rep = 0; rep < 4; rep++) {
        int f = rep * 512 + tid, row = f >> 3, c4 = f & 7;
        ra[rep] = *(const f32x4*)(pb + (size_t)row * SEQN + k0 + c4 * 4);
      }
#pragma unroll
      for (int rep = 0; rep < 2; rep++) {
        int f = rep * 512 + tid, row = f >> 3, c4 = f & 7;
        rbv[rep] = *(const h16x4*)(vb + (size_t)row * SEQN + k0 + c4 * 4);
      }
    } else {
      const int k0 = (t - 64) * 32;
      const bool clean = (t >= 72) && (t < 128);
#pragma unroll
      for (int rep = 0; rep < 4; rep++) {
        int f = rep * 512 + tid, row = f >> 3, c4 = f & 7;
        int jb = k0 + c4 * 4 + row - 255;
        const float* pr = pb + (size_t)row * SEQN;
        f32x4 v4;
        if (clean) {
          __builtin_memcpy(&v4, pr + jb, 16);
        } else {
#pragma unroll
          for (int e = 0; e < 4; e++) {
            int j = jb + e;
            v4[e] = (j >= 0 && j < SEQN) ? pr[j] : 0.f;
          }
        }
        ra[rep] = v4;
      }
#pragma unroll
      for (int rep = 0; rep < 2; rep++) {
        int f = rep * 512 + tid, row = f >> 3, c4 = f & 7;
        rbv[rep] = *(const h16x4*)(wb + (size_t)row * WPAD + k0 + c4 * 4);
      }
    }
  };
  auto WRITE = [&](char* lb) {
#pragma unroll
    for (int rep = 0; rep < 4; rep++) {
      int f = rep * 512 + tid, row = f >> 3, c4 = f & 7;
      h16x4 ha = {(_Float16)ra[rep][0], (_Float16)ra[rep][1],
                  (_Float16)ra[rep][2], (_Float16)ra[rep][3]};
      *(h16x4*)(lb + swzw(row, c4)) = ha;
    }
#pragma unroll
    for (int rep = 0; rep < 2; rep++) {
      int f = rep * 512 + tid, row = f >> 3, c4 = f & 7;
      *(h16x4*)(lb + 16384 + swzw(row, c4)) = rbv[rep];
    }
  };

  LOADREGS(0);
  WRITE(smem);
  LOADREGS(1);
  __syncthreads();

  for (int t = 0; t < 136; t++) {
    char* lb = smem + (t & 1) * 24576;
    if (t + 1 < 136) WRITE(smem + ((t + 1) & 1) * 24576);
    h16x8 af[4], bf[4];
#pragma unroll
    for (int mf = 0; mf < 4; mf++)
      af[mf] = *(const h16x8*)(lb + swzr(wm * 64 + mf * 16 + r16, kg));
#pragma unroll
    for (int nf = 0; nf < 4; nf++)
      bf[nf] = *(const h16x8*)(lb + 16384 + swzr(wn * 64 + nf * 16 + r16, kg));
    if (t + 2 < 136) LOADREGS(t + 2);
#pragma unroll
    for (int mf = 0; mf < 4; mf++)
#pragma unroll
      for (int nf = 0; nf < 4; nf++)
        acc[mf][nf] = __builtin_amdgcn_mfma_f32_16x16x32_f16(af[mf], bf[nf], acc[mf][nf], 0, 0, 0);
    __syncthreads();
  }

#pragma unroll
  for (int mf = 0; mf < 4; mf++)
#pragma unroll
    for (int nf = 0; nf < 4; nf++)
#pragma unroll
      for (int r = 0; r < 4; r++) {
        int ii = wm * 64 + mf * 16 + kg * 4 + r;
        int dd = wn * 64 + nf * 16 + r16;
        outp[(size_t)(b * SEQN + i0 + ii) * DD + d0 + dd] = acc[mf][nf][r];
      }
}

extern "C" void kernel_launch(void* const* d_in, const int* in_sizes, int n_in,
                              void* d_out, int out_size, void* d_ws, size_t ws_size,
                              hipStream_t stream) {
  const float* q  = (const float*)d_in[0];
  const float* k  = (const float*)d_in[1];
  const float* v  = (const float*)d_in[2];
  const float* wk = (const float*)d_in[3];
  const float* wv = (const float*)d_in[4];

  float* outp = (float*)d_out;
  float* S    = outp + (size_t)NB * SEQN * DD;   // p region of d_out doubles as S

  // ws layout (f16 elems): vT | wvT | qh | kh | wkh = 58.7 MB
  const size_t nVT = (size_t)NB * DD * SEQN;     // 8388608
  const size_t nWV = (size_t)DD * WPAD;          // 2097152
  const size_t nQH = (size_t)NB * SEQN * DD;     // 8388608
  _Float16* vT  = (_Float16*)d_ws;
  _Float16* wvT = vT + nVT;
  _Float16* qh  = wvT + nWV;
  _Float16* kh  = qh + nQH;
  _Float16* wkh = kh + nQH;

  cvt_f16_k<<<dim3(2048), 256, 0, stream>>>(q,  qh,  (long)(nQH / 8));
  cvt_f16_k<<<dim3(2048), 256, 0, stream>>>(k,  kh,  (long)(nQH / 8));
  cvt_f16_k<<<dim3(1024), 256, 0, stream>>>(wk, wkh, (long)((size_t)WROWS * DD / 8));
  transpose_v_k <<<dim3(DD / 32, SEQN / 32, NB), 256, 0, stream>>>(v, vT);
  transpose_wv_k<<<dim3(DD / 32, 128),           256, 0, stream>>>(wv, wvT);

  score_base3_k <<<dim3(SEQN / 128, SEQN / 256, NB), 512, 0, stream>>>(qh, kh, S);
  score_rel3_k  <<<dim3(18, SEQN / 256, NB),         512, 0, stream>>>(qh, wkh, S);
  softmax_rows_k<<<dim3(NB * SEQN / 4),              256, 0, stream>>>(S);
  out_gemm9_k   <<<dim3(256),                        512, 0, stream>>>(S, vT, wvT, outp);
}

// Round 17
// 406.122 us; speedup vs baseline: 1.0610x; 1.0610x over previous
//
#include <hip/hip_runtime.h>

// RelativeAttention B=8, N=2048, D=512, fp32 in, (out[B,N,D], p[B,N,N]) fp32 out.
//
// Round-17: REVERT to round-15 verbatim — the session's measured best
// (405.7 us, absmax 0.0859375). r16's score-geometry change regressed
// (-25us: 72KB LDS -> 2 blocks/CU, K=16 too short to amortize prologue).
// Final configuration:
//   - scores: 128x128 / 4-wave counted-vmcnt gl_lds core (r9-verified)
//   - softmax: lean f32 in-place (r14)
//   - out: 256x128 / 8-wave reg-staged 2-phase (r15, 155.5us, MfmaUtil 19)
// Levers mapped: schedule depth null (r11-13), occupancy null (r7),
// staging-precision negative (r9), score geometry negative (r16),
// out geometry positive (r15). No PMC pipe >23% -> structure ceiling.

#define SEQN 2048
#define DD   512
#define NB   8
#define WROWS 4095   // 2N-1
#define WPAD  4096   // padded row stride for wvT

typedef float     f32x4 __attribute__((ext_vector_type(4)));
typedef _Float16  h16x4 __attribute__((ext_vector_type(4)));
typedef _Float16  h16x8 __attribute__((ext_vector_type(8)));

__device__ __forceinline__ unsigned swzw(int row, int c4) {
  unsigned b = (unsigned)(row * 64 + c4 * 8);
  return b ^ (((unsigned)row & 6u) << 3);
}
__device__ __forceinline__ unsigned swzr(int row, int kg) {
  unsigned b = (unsigned)(row * 64 + kg * 16);
  return b ^ (((unsigned)row & 6u) << 3);
}

typedef const __attribute__((address_space(1))) unsigned int gu32_t;
typedef __attribute__((address_space(3))) unsigned int lu32_t;
__device__ __forceinline__ void gload_lds16(const void* g, void* l) {
  __builtin_amdgcn_global_load_lds((gu32_t*)g, (lu32_t*)l, 16, 0, 0);
}

// ---------------------------------------------------------------------------
// Counted-vmcnt depth-2 gl_lds core (verified r9) — scores: 128x128 tile,
// 4 waves, K-step 32, 3 LDS buffers of 16 KB (A at +0, B at +8192).
// vmcnt(8) = 2 tiles x 4 loads/wave in flight. Read-side XOR swizzle applied
// by pre-swizzling the per-lane GLOBAL source chunk (both-sides rule).
// ---------------------------------------------------------------------------
template <class P>
__device__ __forceinline__ void stage_tile(const P& prov, char* smem, int buf,
                                           int t, int wave, int l4, int cp) {
  char* lb = smem + buf * 16384;
#pragma unroll
  for (int h = 0; h < 2; h++) {
    int R = wave * 32 + h * 16;
    int row = R + l4;
    int c = cp ^ ((row >> 1) & 3);
    gload_lds16((const char*)prov.a_src(t, row) + c * 16, lb + R * 64);
    gload_lds16((const char*)prov.b_src(t, row) + c * 16, lb + 8192 + R * 64);
  }
}

template <int NT, class P>
__device__ __forceinline__ void gemm_core_cnt(const P& prov, char* smem, f32x4 (&acc)[4][4]) {
  const int tid = threadIdx.x;
  const int lane = tid & 63, wave = tid >> 6;
  const int l4 = lane >> 2, cp = lane & 3;
  const int wm = wave >> 1, wn = wave & 1;
  const int r16 = lane & 15, kg = lane >> 4;

  stage_tile(prov, smem, 0, 0, wave, l4, cp);
  stage_tile(prov, smem, 1, 1, wave, l4, cp);
  stage_tile(prov, smem, 2, 2, wave, l4, cp);

  int buf = 0;
  for (int t = 0; t < NT; t++) {
    asm volatile("s_waitcnt vmcnt(8)" ::: "memory");
    __builtin_amdgcn_s_barrier();
    char* lb = smem + buf * 16384;
    h16x8 af[4], bf[4];
#pragma unroll
    for (int mf = 0; mf < 4; mf++)
      af[mf] = *(const h16x8*)(lb + swzr(wm * 64 + mf * 16 + r16, kg));
#pragma unroll
    for (int nf = 0; nf < 4; nf++)
      bf[nf] = *(const h16x8*)(lb + 8192 + swzr(wn * 64 + nf * 16 + r16, kg));
#pragma unroll
    for (int mf = 0; mf < 4; mf++)
#pragma unroll
      for (int nf = 0; nf < 4; nf++)
        acc[mf][nf] = __builtin_amdgcn_mfma_f32_16x16x32_f16(af[mf], bf[nf], acc[mf][nf], 0, 0, 0);
    asm volatile("s_waitcnt lgkmcnt(0)" ::: "memory");
    __builtin_amdgcn_s_barrier();
    int nt2 = t + 3; if (nt2 >= NT) nt2 = NT - 1;   // clamped restage keeps vmcnt counting uniform
    stage_tile(prov, smem, buf, nt2, wave, l4, cp);
    buf = (buf == 2) ? 0 : buf + 1;
  }
}

// ---------------- providers -------------------------------------------------
struct ProvQK {   // base scores: A=q_h rows i, B=k_h rows j (stride 1024 B)
  const char *ar, *br;
  __device__ __forceinline__ const void* a_src(int t, int row) const {
    return ar + (size_t)row * 1024 + (size_t)t * 64;
  }
  __device__ __forceinline__ const void* b_src(int t, int row) const {
    return br + (size_t)row * 1024 + (size_t)t * 64;
  }
};
struct ProvRel {  // rel scores: A=q_h, B=wk_h band rows (clamped)
  const char *ar, *wk; int tb;
  __device__ __forceinline__ const void* a_src(int t, int row) const {
    return ar + (size_t)row * 1024 + (size_t)t * 64;
  }
  __device__ __forceinline__ const void* b_src(int t, int row) const {
    int tr = tb + row; if (tr > WROWS - 1) tr = WROWS - 1;
    return wk + (size_t)tr * 1024 + (size_t)t * 64;
  }
};

// ---------------- f32 -> f16 bulk convert -----------------------------------
__global__ __launch_bounds__(256) void cvt_f16_k(const float* __restrict__ in,
                                                 _Float16* __restrict__ out, long n8) {
  for (long i = (long)blockIdx.x * 256 + threadIdx.x; i < n8; i += (long)gridDim.x * 256) {
    f32x4 a = ((const f32x4*)in)[i * 2];
    f32x4 b = ((const f32x4*)in)[i * 2 + 1];
    h16x8 h = {(_Float16)a[0], (_Float16)a[1], (_Float16)a[2], (_Float16)a[3],
               (_Float16)b[0], (_Float16)b[1], (_Float16)b[2], (_Float16)b[3]};
    ((h16x8*)out)[i] = h;
  }
}

// ---------------- transpose v [B,N,D] f32 -> vT [B,D,N] f16 ----------------
__global__ __launch_bounds__(256) void transpose_v_k(const float* __restrict__ v,
                                                     _Float16* __restrict__ vT) {
  __shared__ float tile[32][33];
  const int d0 = blockIdx.x * 32, j0 = blockIdx.y * 32, b = blockIdx.z;
  const int tid = threadIdx.x;
#pragma unroll
  for (int rep = 0; rep < 4; rep++) {
    int idx = rep * 256 + tid;
    int rr = idx >> 5, cc = idx & 31;
    tile[rr][cc] = v[((size_t)(b * SEQN + j0 + rr)) * DD + d0 + cc];
  }
  __syncthreads();
#pragma unroll
  for (int rep = 0; rep < 4; rep++) {
    int idx = rep * 256 + tid;
    int rr = idx >> 5, cc = idx & 31;
    vT[((size_t)(b * DD + d0 + rr)) * SEQN + j0 + cc] = (_Float16)tile[cc][rr];
  }
}

// ------------- transpose w_v [4095,512] f32 -> wvT [512,4096] f16 -----------
__global__ __launch_bounds__(256) void transpose_wv_k(const float* __restrict__ wv,
                                                      _Float16* __restrict__ wvT) {
  __shared__ float tile[32][33];
  const int d0 = blockIdx.x * 32, r0 = blockIdx.y * 32;
  const int tid = threadIdx.x;
#pragma unroll
  for (int rep = 0; rep < 4; rep++) {
    int idx = rep * 256 + tid;
    int rr = idx >> 5, cc = idx & 31;
    float val = 0.f;
    if (r0 + rr < WROWS) val = wv[(size_t)(r0 + rr) * DD + d0 + cc];
    tile[rr][cc] = val;
  }
  __syncthreads();
#pragma unroll
  for (int rep = 0; rep < 4; rep++) {
    int idx = rep * 256 + tid;
    int rr = idx >> 5, cc = idx & 31;
    wvT[(size_t)(d0 + rr) * WPAD + r0 + cc] = (_Float16)tile[cc][rr];
  }
}

// ---------------- score kernels: counted-vmcnt gl_lds core ------------------
__global__ __launch_bounds__(256) void score_base2_k(const _Float16* __restrict__ qh,
                                                     const _Float16* __restrict__ kh,
                                                     float* __restrict__ S) {
  __shared__ __align__(16) char smem[49152];
  const int j0 = blockIdx.x * 128, i0 = blockIdx.y * 128, b = blockIdx.z;
  const int tid = threadIdx.x, lane = tid & 63, wave = tid >> 6;
  const int wm = wave >> 1, wn = wave & 1, r16 = lane & 15, kg = lane >> 4;

  f32x4 acc[4][4];
#pragma unroll
  for (int mf = 0; mf < 4; mf++)
#pragma unroll
    for (int nf = 0; nf < 4; nf++) acc[mf][nf] = (f32x4){0.f, 0.f, 0.f, 0.f};

  ProvQK prov{(const char*)(qh + (size_t)(b * SEQN + i0) * DD),
              (const char*)(kh + (size_t)(b * SEQN + j0) * DD)};
  gemm_core_cnt<16>(prov, smem, acc);

#pragma unroll
  for (int mf = 0; mf < 4; mf++)
#pragma unroll
    for (int nf = 0; nf < 4; nf++)
#pragma unroll
      for (int r = 0; r < 4; r++) {
        int ii = wm * 64 + mf * 16 + kg * 4 + r;
        int jj = wn * 64 + nf * 16 + r16;
        S[(size_t)(b * SEQN + i0 + ii) * SEQN + j0 + jj] = acc[mf][nf][r];
      }
}

__global__ __launch_bounds__(256) void score_rel2_k(const _Float16* __restrict__ qh,
                                                    const _Float16* __restrict__ wkh,
                                                    float* __restrict__ S) {
  __shared__ __align__(16) char smem[49152];
  const int z = blockIdx.x, i0 = blockIdx.y * 128, b = blockIdx.z;
  const int tid = threadIdx.x, lane = tid & 63, wave = tid >> 6;
  const int wm = wave >> 1, wn = wave & 1, r16 = lane & 15, kg = lane >> 4;
  const int tmin = SEQN - 128 - i0;

  f32x4 acc[4][4];
#pragma unroll
  for (int mf = 0; mf < 4; mf++)
#pragma unroll
    for (int nf = 0; nf < 4; nf++) acc[mf][nf] = (f32x4){0.f, 0.f, 0.f, 0.f};

  ProvRel prov{(const char*)(qh + (size_t)(b * SEQN + i0) * DD),
               (const char*)wkh, tmin + z * 128};
  gemm_core_cnt<16>(prov, smem, acc);

  // scatter-add: band col bc -> j = bc + i' - 127
#pragma unroll
  for (int mf = 0; mf < 4; mf++)
#pragma unroll
    for (int nf = 0; nf < 4; nf++) {
      int bcg = z * 128 + wn * 64 + nf * 16 + r16;
#pragma unroll
      for (int r = 0; r < 4; r++) {
        int ii = wm * 64 + mf * 16 + kg * 4 + r;
        int j = bcg + ii - 127;
        if (bcg <= 2174 && j >= 0 && j < SEQN)
          S[(size_t)(b * SEQN + i0 + ii) * SEQN + j] += acc[mf][nf][r];
      }
    }
}

// ---------------- softmax over rows of S (in place -> p) --------------------
__global__ __launch_bounds__(256) void softmax_rows_k(float* __restrict__ S) {
  const int wid = threadIdx.x >> 6, lane = threadIdx.x & 63;
  const size_t row = (size_t)blockIdx.x * 4 + wid;
  float* p = S + row * SEQN;
  f32x4 x[8];
  float m = -3.4e38f;
#pragma unroll
  for (int c = 0; c < 8; c++) {
    x[c] = *(const f32x4*)(p + c * 256 + lane * 4);
    m = fmaxf(m, fmaxf(fmaxf(x[c][0], x[c][1]), fmaxf(x[c][2], x[c][3])));
  }
#pragma unroll
  for (int off = 32; off > 0; off >>= 1) m = fmaxf(m, __shfl_xor(m, off));
  float s = 0.f;
#pragma unroll
  for (int c = 0; c < 8; c++)
#pragma unroll
    for (int e = 0; e < 4; e++) {
      x[c][e] = __expf(x[c][e] - m);
      s += x[c][e];
    }
#pragma unroll
  for (int off = 32; off > 0; off >>= 1) s += __shfl_xor(s, off);
  float inv = 1.f / s;
#pragma unroll
  for (int c = 0; c < 8; c++) {
    x[c][0] *= inv; x[c][1] *= inv; x[c][2] *= inv; x[c][3] *= inv;
    *(f32x4*)(p + c * 256 + lane * 4) = x[c];
  }
}

// ------- out = p.v + skew(p).w_v — BM=256 x BN=128, 8 waves (r15 best) ------
// 136 K-steps: t in [0,64) = p.v ; t in [64,136) = skew(p).w_v (band 2304,
// j = bc + row - 255; clean t in [72,128)). Reg-prefetch 1 step, 2 x 24KB
// LDS buffers, 1 __syncthreads/step. Staging: 4 A + 2 B slots/thread/step.
__global__ __launch_bounds__(512) void out_gemm9_k(const float* __restrict__ S,
                                                   const _Float16* __restrict__ vT,
                                                   const _Float16* __restrict__ wvT,
                                                   float* __restrict__ outp) {
  __shared__ __align__(16) char smem[49152];
  // decode: 256 blocks = 4 d-tiles x 64 row-tiles; same-rt blocks co-XCD.
  const int bid = blockIdx.x;
  const int xcd = bid & 7, rr = bid >> 3;
  const int x = rr & 3, s8 = rr >> 2;
  const int rt = xcd + 8 * s8;               // [0,64): row-tile, bijective
  const int d0 = x * 128, b = rt >> 3, i0 = (rt & 7) * 256;
  const int tid = threadIdx.x, lane = tid & 63, wave = tid >> 6;
  const int wm = wave >> 1, wn = wave & 1, r16 = lane & 15, kg = lane >> 4;
  const int tmin = SEQN - 256 - i0;          // first band row (>=0, <=1792)

  const float*    pb = S  + (size_t)(b * SEQN + i0) * SEQN;
  const _Float16* vb = vT + (size_t)(b * DD + d0) * SEQN;
  const _Float16* wb = wvT + (size_t)d0 * WPAD + tmin;

  f32x4 acc[4][4];
#pragma unroll
  for (int mf = 0; mf < 4; mf++)
#pragma unroll
    for (int nf = 0; nf < 4; nf++) acc[mf][nf] = (f32x4){0.f, 0.f, 0.f, 0.f};

  f32x4 ra[4];      // 4 A-slots (f32, cvt at LDS-write)
  h16x4 rbv[2];     // 2 B-slots (f16)

  auto LOADREGS = [&](int t) {
    if (t < 64) {
      const int k0 = t * 32;
#pragma unroll
      for (int rep = 0; rep < 4; rep++) {           // A: 2048 slots / 512 thr
        int f = rep * 512 + tid, row = f >> 3, c4 = f & 7;
        ra[rep] = *(const f32x4*)(pb + (size_t)row * SEQN + k0 + c4 * 4);
      }
#pragma unroll
      for (int rep = 0; rep < 2; rep++) {           // B: 1024 slots / 512 thr
        int f = rep * 512 + tid, row = f >> 3, c4 = f & 7;
        rbv[rep] = *(const h16x4*)(vb + (size_t)row * SEQN + k0 + c4 * 4);
      }
    } else {
      const int k0 = (t - 64) * 32;
      const bool clean = (t >= 72) && (t < 128);    // j provably in [0,2048)
#pragma unroll
      for (int rep = 0; rep < 4; rep++) {
        int f = rep * 512 + tid, row = f >> 3, c4 = f & 7;
        int jb = k0 + c4 * 4 + row - 255;
        const float* pr = pb + (size_t)row * SEQN;
        f32x4 v4;
        if (clean) {
          __builtin_memcpy(&v4, pr + jb, 16);       // unpredicated, 4B-aligned
        } else {
#pragma unroll
          for (int e = 0; e < 4; e++) {
            int j = jb + e;
            v4[e] = (j >= 0 && j < SEQN) ? pr[j] : 0.f;
          }
        }
        ra[rep] = v4;
      }
#pragma unroll
      for (int rep = 0; rep < 2; rep++) {
        int f = rep * 512 + tid, row = f >> 3, c4 = f & 7;
        rbv[rep] = *(const h16x4*)(wb + (size_t)row * WPAD + k0 + c4 * 4);
      }
    }
  };
  auto WRITE = [&](char* lb) {
#pragma unroll
    for (int rep = 0; rep < 4; rep++) {             // A region [0, 16384)
      int f = rep * 512 + tid, row = f >> 3, c4 = f & 7;
      h16x4 ha = {(_Float16)ra[rep][0], (_Float16)ra[rep][1],
                  (_Float16)ra[rep][2], (_Float16)ra[rep][3]};
      *(h16x4*)(lb + swzw(row, c4)) = ha;
    }
#pragma unroll
    for (int rep = 0; rep < 2; rep++) {             // B region [16384, 24576)
      int f = rep * 512 + tid, row = f >> 3, c4 = f & 7;
      *(h16x4*)(lb + 16384 + swzw(row, c4)) = rbv[rep];
    }
  };

  LOADREGS(0);
  WRITE(smem);
  LOADREGS(1);                 // tile 1 pending in regs
  __syncthreads();             // tile 0 visible

  for (int t = 0; t < 136; t++) {
    char* lb = smem + (t & 1) * 24576;
    if (t + 1 < 136) WRITE(smem + ((t + 1) & 1) * 24576);   // WAR-safe
    h16x8 af[4], bf[4];
#pragma unroll
    for (int mf = 0; mf < 4; mf++)
      af[mf] = *(const h16x8*)(lb + swzr(wm * 64 + mf * 16 + r16, kg));
#pragma unroll
    for (int nf = 0; nf < 4; nf++)
      bf[nf] = *(const h16x8*)(lb + 16384 + swzr(wn * 64 + nf * 16 + r16, kg));
    if (t + 2 < 136) LOADREGS(t + 2);                        // issue early
#pragma unroll
    for (int mf = 0; mf < 4; mf++)
#pragma unroll
      for (int nf = 0; nf < 4; nf++)
        acc[mf][nf] = __builtin_amdgcn_mfma_f32_16x16x32_f16(af[mf], bf[nf], acc[mf][nf], 0, 0, 0);
    __syncthreads();
  }

#pragma unroll
  for (int mf = 0; mf < 4; mf++)
#pragma unroll
    for (int nf = 0; nf < 4; nf++)
#pragma unroll
      for (int r = 0; r < 4; r++) {
        int ii = wm * 64 + mf * 16 + kg * 4 + r;              // [0,256)
        int dd = wn * 64 + nf * 16 + r16;                     // [0,128)
        outp[(size_t)(b * SEQN + i0 + ii) * DD + d0 + dd] = acc[mf][nf][r];
      }
}

extern "C" void kernel_launch(void* const* d_in, const int* in_sizes, int n_in,
                              void* d_out, int out_size, void* d_ws, size_t ws_size,
                              hipStream_t stream) {
  const float* q  = (const float*)d_in[0];
  const float* k  = (const float*)d_in[1];
  const float* v  = (const float*)d_in[2];
  const float* wk = (const float*)d_in[3];
  const float* wv = (const float*)d_in[4];

  float* outp = (float*)d_out;
  float* S    = outp + (size_t)NB * SEQN * DD;   // p region of d_out doubles as S

  // ws layout (f16 elems): vT | wvT | qh | kh | wkh = 58.7 MB
  const size_t nVT = (size_t)NB * DD * SEQN;     // 8388608
  const size_t nWV = (size_t)DD * WPAD;          // 2097152
  const size_t nQH = (size_t)NB * SEQN * DD;     // 8388608
  _Float16* vT  = (_Float16*)d_ws;
  _Float16* wvT = vT + nVT;
  _Float16* qh  = wvT + nWV;
  _Float16* kh  = qh + nQH;
  _Float16* wkh = kh + nQH;

  cvt_f16_k<<<dim3(2048), 256, 0, stream>>>(q,  qh,  (long)(nQH / 8));
  cvt_f16_k<<<dim3(2048), 256, 0, stream>>>(k,  kh,  (long)(nQH / 8));
  cvt_f16_k<<<dim3(1024), 256, 0, stream>>>(wk, wkh, (long)((size_t)WROWS * DD / 8));
  transpose_v_k <<<dim3(DD / 32, SEQN / 32, NB), 256, 0, stream>>>(v, vT);
  transpose_wv_k<<<dim3(DD / 32, 128),           256, 0, stream>>>(wv, wvT);

  score_base2_k <<<dim3(SEQN / 128, SEQN / 128, NB), 256, 0, stream>>>(qh, kh, S);
  score_rel2_k  <<<dim3(17, SEQN / 128, NB),         256, 0, stream>>>(qh, wkh, S);
  softmax_rows_k<<<dim3(NB * SEQN / 4),              256, 0, stream>>>(S);
  out_gemm9_k   <<<dim3(256),                        512, 0, stream>>>(S, vT, wvT, outp);
}